// Round 1
// baseline (479.504 us; speedup 1.0000x reference)
//
#include <hip/hip_runtime.h>
#include <cstdint>
#include <cstddef>

#define VOCAB 50000
#define EMBED 512
#define COMP  300
#define LW    200

// ---------------------------------------------------------------------------
// Kernel A: transpose W_hidden [EMBED, VOCAB] -> Wt [VOCAB, EMBED] in d_ws.
// 32x32 LDS tile, +1 pad to kill bank conflicts. ~205 MB traffic, coalesced.
// ---------------------------------------------------------------------------
__global__ void transpose_kernel(const float* __restrict__ in, float* __restrict__ out) {
    __shared__ float tile[32][33];
    int wBase = blockIdx.x * 32;
    int eBase = blockIdx.y * 32;
    int tx = threadIdx.x, ty = threadIdx.y;
#pragma unroll
    for (int j = 0; j < 4; ++j) {
        int e = eBase + ty + j * 8;
        int w = wBase + tx;
        if (w < VOCAB) tile[ty + j * 8][tx] = in[(size_t)e * VOCAB + w];
    }
    __syncthreads();
#pragma unroll
    for (int j = 0; j < 4; ++j) {
        int w = wBase + ty + j * 8;
        int e = eBase + tx;
        if (w < VOCAB) out[(size_t)w * EMBED + e] = tile[tx][ty + j * 8];
    }
}

// ---------------------------------------------------------------------------
// Kernel B: one block (512 threads) per batch row.
//  1. load 200 word ids to LDS, dedup (binary BOW: duplicates collapse to 1)
//  2. thread t accumulates hidden[e=t] = tanh(b_h[t] + sum_w Wt[w*512+t])
//     -> coalesced 2KB row reads of Wt (L3-resident)
//  3. thread c<300: logit[c] = b_pi[c] + dot(hidden, W_pi[c,:]) (float4)
//  4. block softmax over 300, write pi[c*B + i]
// ---------------------------------------------------------------------------
__global__ __launch_bounds__(512) void bow_mdn_kernel(
    const int* __restrict__ words, const float* __restrict__ Wt,
    const float* __restrict__ b_hidden, const float* __restrict__ W_pi,
    const float* __restrict__ b_pi, float* __restrict__ pi_out, int B)
{
    __shared__ int   swords[LW];
    __shared__ int   skeep[LW];
    __shared__ float shid[EMBED];
    __shared__ float red[512];

    const int i = blockIdx.x;
    const int t = threadIdx.x;

    if (t < LW) swords[t] = words[(size_t)i * LW + t];
    __syncthreads();
    if (t < LW) {
        int w = swords[t];
        int keep = 1;
        for (int j = 0; j < t; ++j)
            if (swords[j] == w) { keep = 0; break; }
        skeep[t] = keep;
    }
    __syncthreads();

    // hidden accumulation: thread t handles embedding dim e = t
    float acc = b_hidden[t];
    for (int l = 0; l < LW; ++l) {
        if (skeep[l]) {                      // wave-uniform branch
            acc += Wt[(size_t)swords[l] * EMBED + t];
        }
    }
    shid[t] = tanhf(acc);
    __syncthreads();

    // logits: thread c < 300 dots hidden with W_pi row c (rows L2-resident)
    float logit = -INFINITY;
    if (t < COMP) {
        const float4* wp = (const float4*)(W_pi + (size_t)t * EMBED);
        const float4* h4 = (const float4*)shid;
        float a = b_pi[t];
#pragma unroll 8
        for (int k = 0; k < EMBED / 4; ++k) {
            float4 h = h4[k];
            float4 w = wp[k];
            a += h.x * w.x + h.y * w.y + h.z * w.z + h.w * w.w;
        }
        logit = a;
    }

    // block softmax: max
    red[t] = logit;
    __syncthreads();
    for (int s = 256; s > 0; s >>= 1) {
        if (t < s) red[t] = fmaxf(red[t], red[t + s]);
        __syncthreads();
    }
    float m = red[0];
    __syncthreads();

    float e = (t < COMP) ? expf(logit - m) : 0.0f;
    red[t] = e;
    __syncthreads();
    for (int s = 256; s > 0; s >>= 1) {
        if (t < s) red[t] += red[t + s];
        __syncthreads();
    }
    float inv = 1.0f / red[0];

    if (t < COMP) pi_out[(size_t)t * B + i] = e * inv;
}

// ---------------------------------------------------------------------------
// Kernel C: sigma_out = exp(sigma) [300,2], mu passthrough [300,2]
// out layout after pi: [sigma_out (600), mu (600)]
// ---------------------------------------------------------------------------
__global__ void tail_kernel(const float* __restrict__ mu, const float* __restrict__ sigma,
                            float* __restrict__ out_tail) {
    int t = blockIdx.x * blockDim.x + threadIdx.x;
    if (t < COMP * 2) {
        out_tail[t]            = expf(sigma[t]);  // sigma_out
        out_tail[COMP * 2 + t] = mu[t];           // mu
    }
}

extern "C" void kernel_launch(void* const* d_in, const int* in_sizes, int n_in,
                              void* d_out, int out_size, void* d_ws, size_t ws_size,
                              hipStream_t stream) {
    const int*   words    = (const int*)d_in[0];
    // d_in[1] = features (unused by reference outputs)
    // d_in[2] = mask (unused)
    const float* W_hidden = (const float*)d_in[3];
    const float* b_hidden = (const float*)d_in[4];
    const float* W_pi     = (const float*)d_in[5];
    const float* b_pi     = (const float*)d_in[6];
    const float* mu       = (const float*)d_in[7];
    const float* sigma    = (const float*)d_in[8];
    float* out = (float*)d_out;

    const int B = in_sizes[0] / LW;

    float* Wt = (float*)d_ws;  // VOCAB*EMBED*4 = 102.4 MB

    dim3 tb(32, 8);
    dim3 tg((VOCAB + 31) / 32, EMBED / 32);
    hipLaunchKernelGGL(transpose_kernel, tg, tb, 0, stream, W_hidden, Wt);

    hipLaunchKernelGGL(bow_mdn_kernel, dim3(B), dim3(512), 0, stream,
                       words, Wt, b_hidden, W_pi, b_pi, out, B);

    hipLaunchKernelGGL(tail_kernel, dim3(3), dim3(256), 0, stream,
                       mu, sigma, out + (size_t)COMP * B);
}

// Round 2
// 477.394 us; speedup vs baseline: 1.0044x; 1.0044x over previous
//
#include <hip/hip_runtime.h>
#include <cstdint>
#include <cstddef>

#define VOCAB 50000
#define EMBED 512
#define COMP  300
#define LW    200

// ---------------------------------------------------------------------------
// Kernel A: transpose W_hidden [EMBED, VOCAB] -> Wt [VOCAB, EMBED].
// Tile: 32 e-rows x 128 w-cols, float4 on both global sides.
// LDS row stride 132 floats (528B, 16B-aligned rows). 256 threads.
// ---------------------------------------------------------------------------
__global__ __launch_bounds__(256) void transpose_kernel(
    const float* __restrict__ in, float* __restrict__ out)
{
    __shared__ __align__(16) float tile[32 * 132];
    const int wBase = blockIdx.x * 128;
    const int eBase = blockIdx.y * 32;
    const int s = threadIdx.x;

    // read: 32 rows x 32 float4-cols = 1024 float4 loads, 4 per thread
    {
        const int col4 = s & 31;      // which float4 within the 128-w row
        const int erow = s >> 5;      // 0..7
        const int w = wBase + col4 * 4;
#pragma unroll
        for (int j = 0; j < 4; ++j) {
            const int el = erow + j * 8;
            if (w < VOCAB) {
                const float4 v = *(const float4*)&in[(size_t)(eBase + el) * VOCAB + w];
                *(float4*)&tile[el * 132 + col4 * 4] = v;
            }
        }
    }
    __syncthreads();

    // write: 128 w-rows x 8 e-float4-groups = 1024 float4 stores, 4 per thread
    {
        const int grp = s & 7;        // e float4 group (e_local = grp*4)
        const int wrow = s >> 3;      // 0..31
#pragma unroll
        for (int j = 0; j < 4; ++j) {
            const int wl = wrow + j * 32;
            const int w = wBase + wl;
            if (w < VOCAB) {
                float4 v;
                v.x = tile[(grp * 4 + 0) * 132 + wl];
                v.y = tile[(grp * 4 + 1) * 132 + wl];
                v.z = tile[(grp * 4 + 2) * 132 + wl];
                v.w = tile[(grp * 4 + 3) * 132 + wl];
                *(float4*)&out[(size_t)w * EMBED + eBase + grp * 4] = v;
            }
        }
    }
}

// ---------------------------------------------------------------------------
// Kernel B: one block (256 threads) per batch row. Thread t owns dims 2t,2t+1.
//  1. words -> LDS; branch-free O(L^2) dedup -> multiplier skeepf (dup -> 0)
//  2. branch-free unrolled gather: acc += skeepf[l] * Wt[word[l]][2t..2t+1]
//  3. tanh -> shid; logits: thread t does comp t (+ comp 256+t for t<44)
//  4. wave-shuffle softmax, scatter pi[c*B + i]
// ---------------------------------------------------------------------------
__global__ __launch_bounds__(256) void bow_mdn_kernel(
    const int* __restrict__ words, const float* __restrict__ Wt,
    const float* __restrict__ b_hidden, const float* __restrict__ W_pi,
    const float* __restrict__ b_pi, float* __restrict__ pi_out, int B)
{
    __shared__ int   swords[LW];
    __shared__ int   soff[LW];     // word * (EMBED/2), float2 index
    __shared__ float skeepf[LW];
    __shared__ __align__(16) float shid[EMBED];
    __shared__ float sredA[4];
    __shared__ float sredB[4];

    const int i = blockIdx.x;
    const int t = threadIdx.x;

    if (t < LW) swords[t] = words[(size_t)i * LW + t];
    __syncthreads();

    if (t < LW) {
        const int w = swords[t];
        int dup = 0;
#pragma unroll 8
        for (int j = 0; j < LW; ++j)
            dup |= (swords[j] == w) & (j < t);
        soff[t] = w * (EMBED / 2);
        skeepf[t] = dup ? 0.0f : 1.0f;
    }
    __syncthreads();

    // gather: branch-free, unrolled -> many outstanding float2 loads
    const float2* __restrict__ W2 = (const float2*)Wt;
    float2 acc = ((const float2*)b_hidden)[t];
#pragma unroll 8
    for (int l = 0; l < LW; ++l) {
        const float m = skeepf[l];
        const float2 v = W2[soff[l] + t];
        acc.x = fmaf(m, v.x, acc.x);
        acc.y = fmaf(m, v.y, acc.y);
    }
    shid[2 * t]     = tanhf(acc.x);
    shid[2 * t + 1] = tanhf(acc.y);
    __syncthreads();

    // logits: comp c0 = t (all threads), c1 = 256+t (t < COMP-256)
    const bool has2 = (t < COMP - 256);
    float a0 = b_pi[t];
    float a1 = has2 ? b_pi[256 + t] : -INFINITY;
    {
        const float4* __restrict__ h4 = (const float4*)shid;
        const float4* __restrict__ w0 = (const float4*)(W_pi + (size_t)t * EMBED);
        const float4* __restrict__ w1 = (const float4*)(W_pi + (size_t)(256 + t) * EMBED);
#pragma unroll 4
        for (int k = 0; k < EMBED / 4; ++k) {
            const float4 h = h4[k];
            const float4 f0 = w0[k];
            a0 += h.x * f0.x + h.y * f0.y + h.z * f0.z + h.w * f0.w;
            if (has2) {
                const float4 f1 = w1[k];
                a1 += h.x * f1.x + h.y * f1.y + h.z * f1.z + h.w * f1.w;
            }
        }
    }

    // block max via wave shuffle (4 waves)
    float m = fmaxf(a0, a1);
#pragma unroll
    for (int o = 32; o > 0; o >>= 1) m = fmaxf(m, __shfl_down(m, o));
    if ((t & 63) == 0) sredA[t >> 6] = m;
    __syncthreads();
    m = fmaxf(fmaxf(sredA[0], sredA[1]), fmaxf(sredA[2], sredA[3]));

    const float e0 = __expf(a0 - m);
    const float e1 = has2 ? __expf(a1 - m) : 0.0f;
    float ssum = e0 + e1;
#pragma unroll
    for (int o = 32; o > 0; o >>= 1) ssum += __shfl_down(ssum, o);
    if ((t & 63) == 0) sredB[t >> 6] = ssum;
    __syncthreads();
    const float inv = 1.0f / (sredB[0] + sredB[1] + sredB[2] + sredB[3]);

    pi_out[(size_t)t * B + i] = e0 * inv;
    if (has2) pi_out[(size_t)(256 + t) * B + i] = e1 * inv;
}

// ---------------------------------------------------------------------------
// Kernel C: sigma_out = exp(sigma) [300,2], mu passthrough [300,2]
// ---------------------------------------------------------------------------
__global__ void tail_kernel(const float* __restrict__ mu, const float* __restrict__ sigma,
                            float* __restrict__ out_tail) {
    int t = blockIdx.x * blockDim.x + threadIdx.x;
    if (t < COMP * 2) {
        out_tail[t]            = expf(sigma[t]);  // sigma_out
        out_tail[COMP * 2 + t] = mu[t];           // mu
    }
}

extern "C" void kernel_launch(void* const* d_in, const int* in_sizes, int n_in,
                              void* d_out, int out_size, void* d_ws, size_t ws_size,
                              hipStream_t stream) {
    const int*   words    = (const int*)d_in[0];
    const float* W_hidden = (const float*)d_in[3];
    const float* b_hidden = (const float*)d_in[4];
    const float* W_pi     = (const float*)d_in[5];
    const float* b_pi     = (const float*)d_in[6];
    const float* mu       = (const float*)d_in[7];
    const float* sigma    = (const float*)d_in[8];
    float* out = (float*)d_out;

    const int B = in_sizes[0] / LW;

    float* Wt = (float*)d_ws;  // VOCAB*EMBED*4 = 102.4 MB

    dim3 tg((VOCAB + 127) / 128, EMBED / 32);
    hipLaunchKernelGGL(transpose_kernel, tg, dim3(256), 0, stream, W_hidden, Wt);

    hipLaunchKernelGGL(bow_mdn_kernel, dim3(B), dim3(256), 0, stream,
                       words, Wt, b_hidden, W_pi, b_pi, out, B);

    hipLaunchKernelGGL(tail_kernel, dim3(3), dim3(256), 0, stream,
                       mu, sigma, out + (size_t)COMP * B);
}